// Round 9
// baseline (118.791 us; speedup 1.0000x reference)
//
#include <hip/hip_runtime.h>
#include <hip/hip_bf16.h>

// SupCon loss, N=8192, D=128, T=0.1.
// R14: pipeline the sweep (single variable vs R13). R13 killed the spills
// (WRITE_SIZE scratch gone, 94.25us total, new best); cross-round budget
// arithmetic (R6 fit: fill 41.2 + norm/memsets/gaps ~24-26) puts the sweep
// at ~26us vs a ~10-12us pipe floor -- the gap is R13's stage->barrier->
// compute serialization (L2 latency+BW of each 32KB chunk exposed, x4).
// Fix = guide's minimal 2-phase: double-buffer 2x32KB, ISSUE next stage ->
// compute current -> ONE barrier per chunk (prefetch lands under ~3000cy
// of MFMA+exp, so the vmcnt(0)-at-barrier drain is free; the barrier also
// fences buffer reuse). 8-wave blocks (512thr), grid 512 = 32 rowblks x 16
// sweeps -> 64KB LDS/block, 2 blocks/CU, still 16 waves/CU; staging
// traffic halves. Dual MFMA chains (even/odd f) now fit: live ~102 <= 128,
// tier pinned via waves_per_eu(4,4) (the R13 discovery: pin BOTH sides).
//
// Math: loss_i = (cm1_i*lse_i - 10*(cd_i - sd_i))/(cm1_i+tiny)
//   lse_i = 10 + ln(sum_{j!=i} e^{s_ij-10}); se accumulated INCLUDING
//   diagonal; diag e^{10*sd-10} subtracted in finalize. cd_i = x_i .
//   classsum[lab_i], sd_i = x_i . x_i (bf16-rounded, matches MFMA path).

typedef __bf16 bf16_t;
typedef __bf16 bf16x2 __attribute__((ext_vector_type(2)));
typedef __bf16 bf16x8 __attribute__((ext_vector_type(8)));
typedef float f32x16 __attribute__((ext_vector_type(16)));

#define NN 8192
#define DIM 128
#define SWEEP 16                  // column-sweep splits (partial arrays)
#define SMALL_VAL 1.17549435e-38f
#define L2E10 14.4269504089f      // 10*log2(e)
#define LN2 0.69314718056f

// Swizzle: X[row][d] at (row>>5)*4096 + (d>>4)*512 + ((d>>3)&1)*256 + (row&31)*8 + (d&7)
__device__ inline size_t swz(int row, int lane) {
    int f = lane >> 3, hh = (lane >> 2) & 1, j = (lane & 3) << 1;
    return ((size_t)(row >> 5) * 4096) + f * 512 + hh * 256 + (row & 31) * 8 + j;
}

// DPP-add step: v += dpp_perm(v). bound_ctrl=1 -> OOB lanes read 0.
#define DPPADD(v, ctrl, rmask)                                                         \
    do {                                                                               \
        int _t = __builtin_amdgcn_update_dpp(0, __float_as_int((v)), (ctrl), (rmask),  \
                                             0xf, true);                               \
        (v) += __int_as_float(_t);                                                     \
    } while (0)

// Sum over each 32-lane half; result valid in lane 31 (h=0) and lane 63 (h=1).
__device__ inline float half32_sum(float v) {
    DPPADD(v, 0x111, 0xf);   // row_shr:1
    DPPADD(v, 0x112, 0xf);   // row_shr:2
    DPPADD(v, 0x114, 0xf);   // row_shr:4
    DPPADD(v, 0x118, 0xf);   // row_shr:8
    DPPADD(v, 0x142, 0xa);   // row_bcast:15 into rows 1,3 -> lanes 31/63 full
    return v;
}

// async global->LDS, 16B per lane; LDS dest = uniform base + lane*16.
__device__ inline void gload_lds16(const bf16_t* g, bf16_t* l) {
    __builtin_amdgcn_global_load_lds(
        (const __attribute__((address_space(1))) unsigned int*)g,
        (__attribute__((address_space(3))) unsigned int*)l, 16, 0, 0);
}

// --- fused normalize + class-sum + per-row finalize scalars ---
__global__ __launch_bounds__(256) void norm_csum(const float* __restrict__ emb,
                                                 const int* __restrict__ labels,
                                                 bf16_t* __restrict__ xsw,
                                                 float* __restrict__ cd_arr,
                                                 float* __restrict__ sd_arr,
                                                 float* __restrict__ cm1_arr,
                                                 float* __restrict__ out) {
    __shared__ float cs[DIM];
    __shared__ int rowlist[96];
    __shared__ int nrows;
    int cls = blockIdx.x;                      // 1024 blocks; labels < 1000
    int wv = threadIdx.x >> 6, lane = threadIdx.x & 63;
    if (threadIdx.x < DIM) cs[threadIdx.x] = 0.f;
    if (threadIdx.x == 0) nrows = 0;
    if (cls == 0 && threadIdx.x == 0) *out = 0.f;
    __syncthreads();

    float s0 = 0.f, s1 = 0.f;
    const int4* lab4 = (const int4*)(labels + wv * 2048);       // wave's quarter
#pragma unroll
    for (int it = 0; it < 8; ++it) {
        int4 l = lab4[it * 64 + lane];
        int base = wv * 2048 + it * 256;
#pragma unroll
        for (int cmp = 0; cmp < 4; ++cmp) {
            int li = (cmp == 0) ? l.x : (cmp == 1) ? l.y : (cmp == 2) ? l.z : l.w;
            unsigned long long m = __ballot(li == cls);
            while (m) {                         // wave-uniform loop, ~2 rows/wave avg
                int bb = __builtin_ctzll(m);
                m &= m - 1;
                int row = base + 4 * bb + cmp;
                float2 v = ((const float2*)emb)[row * 64 + lane];
                float ss = fmaf(v.x, v.x, v.y * v.y);
#pragma unroll
                for (int mm = 1; mm < 64; mm <<= 1) ss += __shfl_xor(ss, mm, 64);
                float inv = 1.0f / fmaxf(sqrtf(ss), 1e-12f);
                bf16x2 o; o.x = (bf16_t)(v.x * inv); o.y = (bf16_t)(v.y * inv);
                *(bf16x2*)(xsw + swz(row, lane)) = o;
                s0 += (float)o.x; s1 += (float)o.y;     // bf16-rounded, matches MFMA
                if (lane == 0) {
                    int idx = atomicAdd(&nrows, 1);
                    if (idx < 96) rowlist[idx] = row;
                }
            }
        }
    }
    atomicAdd(&cs[2 * lane], s0);
    atomicAdd(&cs[2 * lane + 1], s1);
    __syncthreads();
    int n = nrows;
    for (int k = wv; k < n; k += 4) {          // per-row cd/sd (rows split over waves)
        int row = rowlist[k];
        bf16x2 xv = *(const bf16x2*)(xsw + swz(row, lane));
        float x0 = (float)xv.x, x1 = (float)xv.y;
        float cdp = fmaf(x0, cs[2 * lane], x1 * cs[2 * lane + 1]);
        float sdp = fmaf(x0, x0, x1 * x1);
#pragma unroll
        for (int mm = 1; mm < 64; mm <<= 1) {
            cdp += __shfl_xor(cdp, mm, 64);
            sdp += __shfl_xor(sdp, mm, 64);
        }
        if (lane == 0) {
            cd_arr[row] = cdp; sd_arr[row] = sdp; cm1_arr[row] = (float)(n - 1);
        }
    }
}

// --- main: 512 blocks = (rb 0..31) x (s 0..15), 8 waves each. Wave wv owns
// 32-row band I = rb*8+wv; sweeps chunks ch = s + 16*k, k=0..3 (128 cols).
// Double-buffered staging: issue next chunk -> compute current -> barrier.
// Full matrix; row sums complete in regs; plain stores.
// C layout (m74/m101): col = lane&31, row = (r&3)+8*(r>>2)+4*(lane>>5).
__global__
__attribute__((amdgpu_flat_work_group_size(512, 512)))
__attribute__((amdgpu_waves_per_eu(4, 4)))     // pin 128-VGPR tier exactly
void supcon_sweep(const bf16_t* __restrict__ xsw,
                  float* __restrict__ se_part) {
    __shared__ bf16_t bst[2][4 * 4096];        // 2 x 32 KB -> 2 blocks/CU, 16 w/CU

    int s = blockIdx.x & 15, rb = blockIdx.x >> 4;
    int wv = threadIdx.x >> 6, lane = threadIdx.x & 63;
    int I = rb * 8 + wv;                       // 32-row band (0..255)
    int c = lane & 31, h = lane >> 5;
    int laneoff = h * 256 + c * 8;

    // A frags (global, L2-resident xsw): 32 VGPRs, loaded once
    const bf16_t* abase = xsw + (size_t)I * 4096 + laneoff;
    bf16x8 a[8];
#pragma unroll
    for (int f = 0; f < 8; ++f) a[f] = *(const bf16x8*)(abase + f * 512);

    float se[16];
#pragma unroll
    for (int r = 0; r < 16; ++r) se[r] = 0.f;

    // prologue: stage chunk 0 (ch = s) into buf 0; 4 x 1KB sub-chunks/wave
    {
        const bf16_t* gsrc = xsw + (size_t)s * 16384;
#pragma unroll
        for (int i = 0; i < 4; ++i) {
            int kk = i * 8 + wv;
            gload_lds16(gsrc + kk * 512 + lane * 8, &bst[0][kk * 512]);
        }
    }
    __syncthreads();                           // chunk 0 landed

#pragma unroll 1
    for (int k = 0; k < 4; ++k) {
        // issue NEXT chunk's stage first; it lands under this chunk's compute
        if (k < 3) {
            const bf16_t* gsrc = xsw + (size_t)(s + 16 * (k + 1)) * 16384;
            bf16_t* dbuf = &bst[(k + 1) & 1][0];
#pragma unroll
            for (int i = 0; i < 4; ++i) {
                int kk = i * 8 + wv;
                gload_lds16(gsrc + kk * 512 + lane * 8, dbuf + kk * 512);
            }
        }
        const bf16_t* bb = &bst[k & 1][0];

#pragma unroll
        for (int t = 0; t < 4; ++t) {
            f32x16 acc0, acc1;                 // dual chains: even/odd K-slices
#pragma unroll
            for (int r = 0; r < 16; ++r) { acc0[r] = 0.f; acc1[r] = 0.f; }
            const bf16_t* bt = bb + t * 4096 + laneoff;
#pragma unroll
            for (int f = 0; f < 8; f += 2) {
                bf16x8 b0 = *(const bf16x8*)(bt + f * 512);
                bf16x8 b1 = *(const bf16x8*)(bt + (f + 1) * 512);
                acc0 = __builtin_amdgcn_mfma_f32_32x32x16_bf16(a[f], b0, acc0, 0, 0, 0);
                acc1 = __builtin_amdgcn_mfma_f32_32x32x16_bf16(a[f + 1], b1, acc1, 0, 0, 0);
            }
#pragma unroll
            for (int r = 0; r < 16; ++r)
                se[r] += __builtin_amdgcn_exp2f(fmaf(acc0[r] + acc1[r], L2E10, -L2E10));
        }
        // one barrier per chunk: (a) all waves done reading buf[k&1] before
        // anyone re-stages it next iteration; (b) vmcnt drained -> next
        // chunk's stage (issued before compute) is complete.
        __syncthreads();
    }

    // row sums: DPP reduce across 32 col-lanes; results in lane 31 (h=0)
    // and lane 63 (h=1). Plain stores, no atomics; (s,row) unique writer.
#pragma unroll
    for (int r = 0; r < 16; ++r) se[r] = half32_sum(se[r]);
    if (c == 31) {
        float* dst = se_part + (size_t)s * NN + I * 32 + 4 * h;
#pragma unroll
        for (int r = 0; r < 16; ++r)
            dst[(r & 3) + 8 * (r >> 2)] = se[r];
    }
}

// --- finalize: sum 16 partials, elementwise loss, block reduce ---
__global__ __launch_bounds__(256) void finalize_kernel(const float* __restrict__ se_part,
                                                       const float* __restrict__ cd_arr,
                                                       const float* __restrict__ sd_arr,
                                                       const float* __restrict__ cm1_arr,
                                                       float* __restrict__ out) {
    __shared__ float part[4];
    int i = blockIdx.x * 256 + threadIdx.x;
    float sev_raw = 0.f;
#pragma unroll
    for (int s = 0; s < SWEEP; ++s) sev_raw += se_part[(size_t)s * NN + i];
    float sd = sd_arr[i], cd = cd_arr[i], cm1 = cm1_arr[i];
    float diag = __builtin_amdgcn_exp2f(fmaf(sd, L2E10, -L2E10));
    float sev  = fmaxf(sev_raw - diag, 1e-30f);
    float lse  = fmaf(__builtin_amdgcn_logf(sev), LN2, 10.f);   // v_log = log2
    float loss = (cm1 * lse - 10.f * (cd - sd)) / (cm1 + SMALL_VAL);
#pragma unroll
    for (int m = 1; m < 64; m <<= 1) loss += __shfl_xor(loss, m, 64);
    int wv = threadIdx.x >> 6;
    if ((threadIdx.x & 63) == 0) part[wv] = loss;
    __syncthreads();
    if (threadIdx.x == 0) atomicAdd(out, part[0] + part[1] + part[2] + part[3]);
}

extern "C" void kernel_launch(void* const* d_in, const int* in_sizes, int n_in,
                              void* d_out, int out_size, void* d_ws, size_t ws_size,
                              hipStream_t stream) {
    const float* emb  = (const float*)d_in[0];
    const int* labels = (const int*)d_in[1];

    char* ws = (char*)d_ws;
    bf16_t* xsw   = (bf16_t*)ws;                          // 2 MB swizzled normalized X
    float* separt = (float*)(ws + (size_t)NN * DIM * 2);  // 512 KB (16 x 8192)
    float* cd     = separt + (size_t)SWEEP * NN;          // 32 KB
    float* sd     = cd + NN;                              // 32 KB
    float* cm1    = sd + NN;                              // 32 KB

    norm_csum<<<1024, 256, 0, stream>>>(emb, labels, xsw, cd, sd, cm1, (float*)d_out);
    supcon_sweep<<<512, 512, 0, stream>>>(xsw, separt);
    finalize_kernel<<<NN / 256, 256, 0, stream>>>(separt, cd, sd, cm1, (float*)d_out);
}

// Round 10
// 93.644 us; speedup vs baseline: 1.2685x; 1.2685x over previous
//
#include <hip/hip_runtime.h>
#include <hip/hip_bf16.h>

// SupCon loss, N=8192, D=128, T=0.1.
// R15: R13 + double-buffer pipeline, on a register budget that can't miss.
// Allocator law (R12/R13/R14 triangulated, gfx950 unified VGPR file):
// waves_per_eu(min,_) => total budget 512/min per wave, split arch+accum;
// (4,4) -> 64 arch (R13 fit EXACTLY: arch live 64, acc in accum half;
// R14's dbuf+dual-chain pushed arch to ~75 -> 71MB scratch, 48us).
// Here: (2,2) -> 128 arch vs ~80 arch live (margin ~48). Single acc chain.
// LDS 2x32KB -> 2 blocks/CU, 8 waves/CU, grid 1024 (two co-resident
// rounds/CU). Stage-next ISSUED before compute; one barrier per chunk
// (fences buffer reuse + vmcnt drain lands after ~2500cy of MFMA+exp).
// Floors/CU: ds_read 10.2us, MFMA 6.8us, exp ~7us, overlapped.
//
// Math: loss_i = (cm1_i*lse_i - 10*(cd_i - sd_i))/(cm1_i+tiny)
//   lse_i = 10 + ln(sum_{j!=i} e^{s_ij-10}); se accumulated INCLUDING
//   diagonal; diag e^{10*sd-10} subtracted in finalize. cd_i = x_i .
//   classsum[lab_i], sd_i = x_i . x_i (bf16-rounded, matches MFMA path).

typedef __bf16 bf16_t;
typedef __bf16 bf16x2 __attribute__((ext_vector_type(2)));
typedef __bf16 bf16x8 __attribute__((ext_vector_type(8)));
typedef float f32x16 __attribute__((ext_vector_type(16)));

#define NN 8192
#define DIM 128
#define SWEEP 16                  // column-sweep splits (partial arrays)
#define SMALL_VAL 1.17549435e-38f
#define L2E10 14.4269504089f      // 10*log2(e)
#define LN2 0.69314718056f

// Swizzle: X[row][d] at (row>>5)*4096 + (d>>4)*512 + ((d>>3)&1)*256 + (row&31)*8 + (d&7)
__device__ inline size_t swz(int row, int lane) {
    int f = lane >> 3, hh = (lane >> 2) & 1, j = (lane & 3) << 1;
    return ((size_t)(row >> 5) * 4096) + f * 512 + hh * 256 + (row & 31) * 8 + j;
}

// DPP-add step: v += dpp_perm(v). bound_ctrl=1 -> OOB lanes read 0.
#define DPPADD(v, ctrl, rmask)                                                         \
    do {                                                                               \
        int _t = __builtin_amdgcn_update_dpp(0, __float_as_int((v)), (ctrl), (rmask),  \
                                             0xf, true);                               \
        (v) += __int_as_float(_t);                                                     \
    } while (0)

// Sum over each 32-lane half; result valid in lane 31 (h=0) and lane 63 (h=1).
__device__ inline float half32_sum(float v) {
    DPPADD(v, 0x111, 0xf);   // row_shr:1
    DPPADD(v, 0x112, 0xf);   // row_shr:2
    DPPADD(v, 0x114, 0xf);   // row_shr:4
    DPPADD(v, 0x118, 0xf);   // row_shr:8
    DPPADD(v, 0x142, 0xa);   // row_bcast:15 into rows 1,3 -> lanes 31/63 full
    return v;
}

// async global->LDS, 16B per lane; LDS dest = uniform base + lane*16.
__device__ inline void gload_lds16(const bf16_t* g, bf16_t* l) {
    __builtin_amdgcn_global_load_lds(
        (const __attribute__((address_space(1))) unsigned int*)g,
        (__attribute__((address_space(3))) unsigned int*)l, 16, 0, 0);
}

// --- fused normalize + class-sum + per-row finalize scalars ---
__global__ __launch_bounds__(256) void norm_csum(const float* __restrict__ emb,
                                                 const int* __restrict__ labels,
                                                 bf16_t* __restrict__ xsw,
                                                 float* __restrict__ cd_arr,
                                                 float* __restrict__ sd_arr,
                                                 float* __restrict__ cm1_arr,
                                                 float* __restrict__ out) {
    __shared__ float cs[DIM];
    __shared__ int rowlist[96];
    __shared__ int nrows;
    int cls = blockIdx.x;                      // 1024 blocks; labels < 1000
    int wv = threadIdx.x >> 6, lane = threadIdx.x & 63;
    if (threadIdx.x < DIM) cs[threadIdx.x] = 0.f;
    if (threadIdx.x == 0) nrows = 0;
    if (cls == 0 && threadIdx.x == 0) *out = 0.f;
    __syncthreads();

    float s0 = 0.f, s1 = 0.f;
    const int4* lab4 = (const int4*)(labels + wv * 2048);       // wave's quarter
#pragma unroll
    for (int it = 0; it < 8; ++it) {
        int4 l = lab4[it * 64 + lane];
        int base = wv * 2048 + it * 256;
#pragma unroll
        for (int cmp = 0; cmp < 4; ++cmp) {
            int li = (cmp == 0) ? l.x : (cmp == 1) ? l.y : (cmp == 2) ? l.z : l.w;
            unsigned long long m = __ballot(li == cls);
            while (m) {                         // wave-uniform loop, ~2 rows/wave avg
                int bb = __builtin_ctzll(m);
                m &= m - 1;
                int row = base + 4 * bb + cmp;
                float2 v = ((const float2*)emb)[row * 64 + lane];
                float ss = fmaf(v.x, v.x, v.y * v.y);
#pragma unroll
                for (int mm = 1; mm < 64; mm <<= 1) ss += __shfl_xor(ss, mm, 64);
                float inv = 1.0f / fmaxf(sqrtf(ss), 1e-12f);
                bf16x2 o; o.x = (bf16_t)(v.x * inv); o.y = (bf16_t)(v.y * inv);
                *(bf16x2*)(xsw + swz(row, lane)) = o;
                s0 += (float)o.x; s1 += (float)o.y;     // bf16-rounded, matches MFMA
                if (lane == 0) {
                    int idx = atomicAdd(&nrows, 1);
                    if (idx < 96) rowlist[idx] = row;
                }
            }
        }
    }
    atomicAdd(&cs[2 * lane], s0);
    atomicAdd(&cs[2 * lane + 1], s1);
    __syncthreads();
    int n = nrows;
    for (int k = wv; k < n; k += 4) {          // per-row cd/sd (rows split over waves)
        int row = rowlist[k];
        bf16x2 xv = *(const bf16x2*)(xsw + swz(row, lane));
        float x0 = (float)xv.x, x1 = (float)xv.y;
        float cdp = fmaf(x0, cs[2 * lane], x1 * cs[2 * lane + 1]);
        float sdp = fmaf(x0, x0, x1 * x1);
#pragma unroll
        for (int mm = 1; mm < 64; mm <<= 1) {
            cdp += __shfl_xor(cdp, mm, 64);
            sdp += __shfl_xor(sdp, mm, 64);
        }
        if (lane == 0) {
            cd_arr[row] = cdp; sd_arr[row] = sdp; cm1_arr[row] = (float)(n - 1);
        }
    }
}

// --- main: 1024 blocks = (rb 0..63) x (s 0..15), 4 waves. Wave wv owns
// 32-row band I = rb*4+wv; sweeps chunks ch = s + 16*k, k=0..3 (128 cols).
// Double-buffered: issue next stage -> compute current -> one barrier.
// Full matrix; row sums complete in regs; plain stores.
// C layout (m74/m101): col = lane&31, row = (r&3)+8*(r>>2)+4*(lane>>5).
__global__
__attribute__((amdgpu_flat_work_group_size(256, 256)))
__attribute__((amdgpu_waves_per_eu(2, 2)))     // 256 unified/wave -> 128 arch
void supcon_sweep(const bf16_t* __restrict__ xsw,
                  float* __restrict__ se_part) {
    __shared__ bf16_t bst[2][4 * 4096];        // 2 x 32 KB -> 2 blocks/CU

    int s = blockIdx.x & 15, rb = blockIdx.x >> 4;
    int wv = threadIdx.x >> 6, lane = threadIdx.x & 63;
    int I = rb * 4 + wv;                       // 32-row band (0..255)
    int c = lane & 31, h = lane >> 5;
    int laneoff = h * 256 + c * 8;

    // A frags (global, L2-resident xsw): 32 VGPRs, loaded once
    const bf16_t* abase = xsw + (size_t)I * 4096 + laneoff;
    bf16x8 a[8];
#pragma unroll
    for (int f = 0; f < 8; ++f) a[f] = *(const bf16x8*)(abase + f * 512);

    float se[16];
#pragma unroll
    for (int r = 0; r < 16; ++r) se[r] = 0.f;

    // prologue: stage chunk 0 (ch = s) into buf 0; 8 x 1KB sub-chunks/wave
    {
        const bf16_t* gsrc = xsw + (size_t)s * 16384;
#pragma unroll
        for (int i = 0; i < 8; ++i) {
            int kk = i * 4 + wv;
            gload_lds16(gsrc + kk * 512 + lane * 8, &bst[0][kk * 512]);
        }
    }
    __syncthreads();                           // chunk 0 landed

#pragma unroll 1
    for (int k = 0; k < 4; ++k) {
        // issue NEXT chunk's stage first; lands under this chunk's compute
        if (k < 3) {
            const bf16_t* gsrc = xsw + (size_t)(s + 16 * (k + 1)) * 16384;
            bf16_t* dbuf = &bst[(k + 1) & 1][0];
#pragma unroll
            for (int i = 0; i < 8; ++i) {
                int kk = i * 4 + wv;
                gload_lds16(gsrc + kk * 512 + lane * 8, dbuf + kk * 512);
            }
        }
        const bf16_t* bb = &bst[k & 1][0];

#pragma unroll
        for (int t = 0; t < 4; ++t) {
            f32x16 acc;                        // single chain (R13's fit)
#pragma unroll
            for (int r = 0; r < 16; ++r) acc[r] = 0.f;
            const bf16_t* bt = bb + t * 4096 + laneoff;
#pragma unroll
            for (int f = 0; f < 8; ++f) {      // B frag read at use; 1 live tuple
                bf16x8 bfr = *(const bf16x8*)(bt + f * 512);
                acc = __builtin_amdgcn_mfma_f32_32x32x16_bf16(a[f], bfr, acc, 0, 0, 0);
            }
#pragma unroll
            for (int r = 0; r < 16; ++r)
                se[r] += __builtin_amdgcn_exp2f(fmaf(acc[r], L2E10, -L2E10));
        }
        // one barrier per chunk: (a) all waves done reading buf[k&1] before
        // its re-stage next iteration; (b) vmcnt drained -> prefetched
        // chunk complete (drain issued ~2500cy after the loads).
        __syncthreads();
    }

    // row sums: DPP reduce across 32 col-lanes; results in lane 31 (h=0)
    // and lane 63 (h=1). Plain stores, no atomics; (s,row) unique writer.
#pragma unroll
    for (int r = 0; r < 16; ++r) se[r] = half32_sum(se[r]);
    if (c == 31) {
        float* dst = se_part + (size_t)s * NN + I * 32 + 4 * h;
#pragma unroll
        for (int r = 0; r < 16; ++r)
            dst[(r & 3) + 8 * (r >> 2)] = se[r];
    }
}

// --- finalize: sum 16 partials, elementwise loss, block reduce ---
__global__ __launch_bounds__(256) void finalize_kernel(const float* __restrict__ se_part,
                                                       const float* __restrict__ cd_arr,
                                                       const float* __restrict__ sd_arr,
                                                       const float* __restrict__ cm1_arr,
                                                       float* __restrict__ out) {
    __shared__ float part[4];
    int i = blockIdx.x * 256 + threadIdx.x;
    float sev_raw = 0.f;
#pragma unroll
    for (int s = 0; s < SWEEP; ++s) sev_raw += se_part[(size_t)s * NN + i];
    float sd = sd_arr[i], cd = cd_arr[i], cm1 = cm1_arr[i];
    float diag = __builtin_amdgcn_exp2f(fmaf(sd, L2E10, -L2E10));
    float sev  = fmaxf(sev_raw - diag, 1e-30f);
    float lse  = fmaf(__builtin_amdgcn_logf(sev), LN2, 10.f);   // v_log = log2
    float loss = (cm1 * lse - 10.f * (cd - sd)) / (cm1 + SMALL_VAL);
#pragma unroll
    for (int m = 1; m < 64; m <<= 1) loss += __shfl_xor(loss, m, 64);
    int wv = threadIdx.x >> 6;
    if ((threadIdx.x & 63) == 0) part[wv] = loss;
    __syncthreads();
    if (threadIdx.x == 0) atomicAdd(out, part[0] + part[1] + part[2] + part[3]);
}

extern "C" void kernel_launch(void* const* d_in, const int* in_sizes, int n_in,
                              void* d_out, int out_size, void* d_ws, size_t ws_size,
                              hipStream_t stream) {
    const float* emb  = (const float*)d_in[0];
    const int* labels = (const int*)d_in[1];

    char* ws = (char*)d_ws;
    bf16_t* xsw   = (bf16_t*)ws;                          // 2 MB swizzled normalized X
    float* separt = (float*)(ws + (size_t)NN * DIM * 2);  // 512 KB (16 x 8192)
    float* cd     = separt + (size_t)SWEEP * NN;          // 32 KB
    float* sd     = cd + NN;                              // 32 KB
    float* cm1    = sd + NN;                              // 32 KB

    norm_csum<<<1024, 256, 0, stream>>>(emb, labels, xsw, cd, sd, cm1, (float*)d_out);
    supcon_sweep<<<1024, 256, 0, stream>>>(xsw, separt);
    finalize_kernel<<<NN / 256, 256, 0, stream>>>(separt, cd, sd, cm1, (float*)d_out);
}